// Round 2
// baseline (290.704 us; speedup 1.0000x reference)
//
#include <hip/hip_runtime.h>

// Problem constants
#define T_LEN 512
#define CIN   32
#define HIDN  128
#define TSUB  4
#define NB    64
#define TT    64            // t-tile per conv block
#define NT2   2048          // T_LEN*TSUB (scan steps)
#define COLS  8192          // NB*HIDN (parallel scan lanes)

// ---------------------------------------------------------------------------
// Kernel A: Conv1d(k=3,pad=1) + bias + BN(eval), written to h[t'][b][hid]
// where t' = t*TSUB + s, c = s*HIDN + hid.  Block = (t-tile=64, s, b).
// ---------------------------------------------------------------------------
__global__ __launch_bounds__(256) void conv_bn_kernel(
    const float* __restrict__ x,    // (B, T, CIN)
    const float* __restrict__ w,    // (C_OUT, CIN, 3)
    const float* __restrict__ cb,   // (C_OUT)
    const float* __restrict__ gam,  // (C_OUT)
    const float* __restrict__ bet,  // (C_OUT)
    const float* __restrict__ mean, // (C_OUT)
    const float* __restrict__ var,  // (C_OUT)
    float* __restrict__ h)          // (NT2, NB, HIDN)
{
    __shared__ float xs[66 * 36];    // rows t0-1..t0+64, pad 36 (bank spread + b128 align)
    __shared__ float ws[128 * 100];  // ws[row][j], j=k*32+i, pad 100 (b128 align)
    __shared__ float scs[128];
    __shared__ float bbs[128];

    const int t0  = blockIdx.x * TT;
    const int s   = blockIdx.y;
    const int b   = blockIdx.z;
    const int tid = threadIdx.x;

    // stage x tile (with zero halo for pad=1)
    for (int idx = tid; idx < 66 * 32; idx += 256) {
        int r = idx >> 5, ci = idx & 31;
        int t = t0 + r - 1;
        xs[r * 36 + ci] = (t >= 0 && t < T_LEN) ? x[(b * T_LEN + t) * CIN + ci] : 0.0f;
    }
    // stage weights for the 128 channels of this s: ws[row][k*32+i] = w[c][i][k]
    for (int idx = tid; idx < 128 * 96; idx += 256) {
        int row = idx / 96, j = idx - row * 96;
        int k = j >> 5, i = j & 31;
        ws[row * 100 + j] = w[(s * HIDN + row) * (CIN * 3) + i * 3 + k];
    }
    if (tid < 128) {
        int c = s * HIDN + tid;
        float sc = gam[c] * rsqrtf(var[c] + 1e-5f);
        scs[tid] = sc;
        bbs[tid] = (cb[c] - mean[c]) * sc + bet[c];
    }
    __syncthreads();

    const int tc = tid & 31;   // hid = tc + cc*32 (4 channels per thread)
    const int tt = tid >> 5;   // 0..7, each handles 8 consecutive t

    float acc[4][8];
#pragma unroll
    for (int a = 0; a < 4; ++a)
#pragma unroll
        for (int q = 0; q < 8; ++q) acc[a][q] = 0.0f;

    for (int j0 = 0; j0 < 96; j0 += 4) {   // groups of 4 (i) within one k
        const int k  = j0 >> 5;
        const int i0 = j0 & 31;
        float4 wv[4];
#pragma unroll
        for (int cc = 0; cc < 4; ++cc)
            wv[cc] = *reinterpret_cast<const float4*>(&ws[(tc + cc * 32) * 100 + j0]);
#pragma unroll
        for (int tq = 0; tq < 8; ++tq) {
            // input t = t0 + lt + k - 1 -> xs row = lt + k
            float4 xv = *reinterpret_cast<const float4*>(&xs[(tt * 8 + tq + k) * 36 + i0]);
#pragma unroll
            for (int cc = 0; cc < 4; ++cc) {
                acc[cc][tq] = fmaf(wv[cc].x, xv.x, acc[cc][tq]);
                acc[cc][tq] = fmaf(wv[cc].y, xv.y, acc[cc][tq]);
                acc[cc][tq] = fmaf(wv[cc].z, xv.z, acc[cc][tq]);
                acc[cc][tq] = fmaf(wv[cc].w, xv.w, acc[cc][tq]);
            }
        }
    }

#pragma unroll
    for (int cc = 0; cc < 4; ++cc) {
        const int hid = tc + cc * 32;
        const float sc = scs[hid], bb = bbs[hid];
#pragma unroll
        for (int tq = 0; tq < 8; ++tq) {
            const int t = t0 + tt * 8 + tq;
            h[((t * TSUB + s) * NB + b) * HIDN + hid] = fmaf(acc[cc][tq], sc, bb);
        }
    }
}

// ---------------------------------------------------------------------------
// Kernel B: exact serial LIF scan.  One thread per (b, hid) lane; 2048 steps.
// Register prefetch pipeline (PF=32) hides load latency; op order matches the
// reference elementwise fp32 semantics (no FMA contraction).
// ---------------------------------------------------------------------------
__global__ __launch_bounds__(64) void lif_scan_kernel(
    const float* __restrict__ h,     // (NT2, COLS)
    const float* __restrict__ lifb,  // (HIDN)
    float* __restrict__ out)         // spk (NT2,COLS) then mem (NT2,COLS)
{
    const int col = blockIdx.x * 64 + threadIdx.x;
    const int hid = col & (HIDN - 1);
    float beta = lifb[hid];
    beta = fminf(fmaxf(beta, 0.0f), 1.0f);

    float* __restrict__ spk  = out;
    float* __restrict__ memo = out + (size_t)NT2 * COLS;

    float mem = 0.0f;
    constexpr int PF = 32;
    float hv[PF];
#pragma unroll
    for (int i = 0; i < PF; ++i) hv[i] = h[i * COLS + col];

    for (int t0 = 0; t0 < NT2; t0 += PF) {
        float hn[PF];
        if (t0 + PF < NT2) {
#pragma unroll
            for (int i = 0; i < PF; ++i) hn[i] = h[(t0 + PF + i) * COLS + col];
        }
#pragma unroll
        for (int i = 0; i < PF; ++i) {
            // reset uses PREVIOUS mem (snntorch subtract-reset, detached)
            const float reset = (mem > 1.0f) ? 1.0f : 0.0f;
            // mem = beta*mem + h_t - reset*1.0, separate roundings (match numpy)
            mem = __fsub_rn(__fadd_rn(__fmul_rn(beta, mem), hv[i]), reset);
            const int idx = (t0 + i) * COLS + col;
            spk[idx]  = (mem > 1.0f) ? 1.0f : 0.0f;  // spike_fn(mem - 1) forward
            memo[idx] = mem;
        }
#pragma unroll
        for (int i = 0; i < PF; ++i) hv[i] = hn[i];
    }
}

// ---------------------------------------------------------------------------
extern "C" void kernel_launch(void* const* d_in, const int* in_sizes, int n_in,
                              void* d_out, int out_size, void* d_ws, size_t ws_size,
                              hipStream_t stream) {
    const float* x    = (const float*)d_in[0];
    const float* w    = (const float*)d_in[1];
    const float* cb   = (const float*)d_in[2];
    const float* gam  = (const float*)d_in[3];
    const float* bet  = (const float*)d_in[4];
    const float* mean = (const float*)d_in[5];
    const float* var  = (const float*)d_in[6];
    const float* lifb = (const float*)d_in[7];

    float* h = (float*)d_ws;   // 2048*8192 floats = 64 MiB scratch

    dim3 gA(T_LEN / TT, TSUB, NB);   // (8, 4, 64)
    conv_bn_kernel<<<gA, 256, 0, stream>>>(x, w, cb, gam, bet, mean, var, h);

    lif_scan_kernel<<<COLS / 64, 64, 0, stream>>>(h, lifb, (float*)d_out);
}

// Round 3
// 288.101 us; speedup vs baseline: 1.0090x; 1.0090x over previous
//
#include <hip/hip_runtime.h>

// Problem constants
#define T_LEN 512
#define CIN   32
#define HIDN  128
#define TSUB  4
#define NB    64
#define TT    64            // t-tile per conv block
#define NT2   2048          // T_LEN*TSUB (scan steps)
#define COLS  8192          // NB*HIDN (parallel scan lanes)
#define CHUNK 32            // pass-2 replay chunk length (steps)
#define NCHUNK (NT2 / CHUNK)

// ---------------------------------------------------------------------------
// Kernel A: Conv1d(k=3,pad=1) + bias + BN(eval), written to h[t'][b][hid]
// where t' = t*TSUB + s, c = s*HIDN + hid.  Block = (t-tile=64, s, b).
// (unchanged from round 2 — isolating the scan experiment)
// ---------------------------------------------------------------------------
__global__ __launch_bounds__(256) void conv_bn_kernel(
    const float* __restrict__ x,    // (B, T, CIN)
    const float* __restrict__ w,    // (C_OUT, CIN, 3)
    const float* __restrict__ cb,   // (C_OUT)
    const float* __restrict__ gam,  // (C_OUT)
    const float* __restrict__ bet,  // (C_OUT)
    const float* __restrict__ mean, // (C_OUT)
    const float* __restrict__ var,  // (C_OUT)
    float* __restrict__ h)          // (NT2, NB, HIDN)
{
    __shared__ float xs[66 * 36];
    __shared__ float ws[128 * 100];  // stride 100: (25r+j) mod 32 conflict-free (gcd(25,32)=1)
    __shared__ float scs[128];
    __shared__ float bbs[128];

    const int t0  = blockIdx.x * TT;
    const int s   = blockIdx.y;
    const int b   = blockIdx.z;
    const int tid = threadIdx.x;

    for (int idx = tid; idx < 66 * 32; idx += 256) {
        int r = idx >> 5, ci = idx & 31;
        int t = t0 + r - 1;
        xs[r * 36 + ci] = (t >= 0 && t < T_LEN) ? x[(b * T_LEN + t) * CIN + ci] : 0.0f;
    }
    for (int idx = tid; idx < 128 * 96; idx += 256) {
        int row = idx / 96, j = idx - row * 96;
        int k = j >> 5, i = j & 31;
        ws[row * 100 + j] = w[(s * HIDN + row) * (CIN * 3) + i * 3 + k];
    }
    if (tid < 128) {
        int c = s * HIDN + tid;
        float sc = gam[c] * rsqrtf(var[c] + 1e-5f);
        scs[tid] = sc;
        bbs[tid] = (cb[c] - mean[c]) * sc + bet[c];
    }
    __syncthreads();

    const int tc = tid & 31;   // hid = tc + cc*32 (4 channels per thread)
    const int tt = tid >> 5;   // 0..7, each handles 8 consecutive t

    float acc[4][8];
#pragma unroll
    for (int a = 0; a < 4; ++a)
#pragma unroll
        for (int q = 0; q < 8; ++q) acc[a][q] = 0.0f;

    for (int j0 = 0; j0 < 96; j0 += 4) {
        const int k  = j0 >> 5;
        const int i0 = j0 & 31;
        float4 wv[4];
#pragma unroll
        for (int cc = 0; cc < 4; ++cc)
            wv[cc] = *reinterpret_cast<const float4*>(&ws[(tc + cc * 32) * 100 + j0]);
#pragma unroll
        for (int tq = 0; tq < 8; ++tq) {
            float4 xv = *reinterpret_cast<const float4*>(&xs[(tt * 8 + tq + k) * 36 + i0]);
#pragma unroll
            for (int cc = 0; cc < 4; ++cc) {
                acc[cc][tq] = fmaf(wv[cc].x, xv.x, acc[cc][tq]);
                acc[cc][tq] = fmaf(wv[cc].y, xv.y, acc[cc][tq]);
                acc[cc][tq] = fmaf(wv[cc].z, xv.z, acc[cc][tq]);
                acc[cc][tq] = fmaf(wv[cc].w, xv.w, acc[cc][tq]);
            }
        }
    }

#pragma unroll
    for (int cc = 0; cc < 4; ++cc) {
        const int hid = tc + cc * 32;
        const float sc = scs[hid], bb = bbs[hid];
#pragma unroll
        for (int tq = 0; tq < 8; ++tq) {
            const int t = t0 + tt * 8 + tq;
            h[((t * TSUB + s) * NB + b) * HIDN + hid] = fmaf(acc[cc][tq], sc, bb);
        }
    }
}

// ---------------------------------------------------------------------------
// Kernel B (pass 1): exact serial LIF recurrence, mem only, no spk stores.
// Emits exact fp32 checkpoints into the mem_rec region of d_out at
// t ≡ 31 (mod 32), t < 2047.  Pass 2 later rewrites those cells with
// bit-identical values (benign same-value race; dword stores are atomic).
// Op order matches numpy exactly: ((beta*mem) + h) - reset, 3 roundings.
// ---------------------------------------------------------------------------
__global__ __launch_bounds__(64) void lif_pass1_kernel(
    const float* __restrict__ h,     // (NT2, COLS)
    const float* __restrict__ lifb,  // (HIDN)
    float* __restrict__ out)
{
    const int col = blockIdx.x * 64 + threadIdx.x;
    const int hid = col & (HIDN - 1);
    float beta = lifb[hid];
    beta = fminf(fmaxf(beta, 0.0f), 1.0f);

    float* __restrict__ memo = out + (size_t)NT2 * COLS;

    float mem = 0.0f;
    constexpr int PF = 64;   // deep prefetch: 64 outstanding loads/wave
    float hv[PF];
#pragma unroll
    for (int i = 0; i < PF; ++i) hv[i] = h[i * COLS + col];

    for (int t0 = 0; t0 < NT2; t0 += PF) {
        float hn[PF];
        if (t0 + PF < NT2) {
#pragma unroll
            for (int i = 0; i < PF; ++i) hn[i] = h[(t0 + PF + i) * COLS + col];
        }
#pragma unroll
        for (int i = 0; i < PF; ++i) {
            const float reset = (mem > 1.0f) ? 1.0f : 0.0f;
            mem = __fsub_rn(__fadd_rn(__fmul_rn(beta, mem), hv[i]), reset);
            // checkpoint entering-state for replay chunks (t = t0+i ≡ 31 mod 32)
            if ((i & (CHUNK - 1)) == CHUNK - 1) {
                const int t = t0 + i;
                if (t < NT2 - 1) memo[t * COLS + col] = mem;
            }
        }
#pragma unroll
        for (int i = 0; i < PF; ++i) hv[i] = hn[i];
    }
}

// ---------------------------------------------------------------------------
// Kernel C (pass 2): 64 chunks x 8192 lanes replay 32 steps each from the
// exact checkpoint and emit all spk/mem outputs. 8192 waves -> full device,
// write-bandwidth-bound.
// ---------------------------------------------------------------------------
__global__ __launch_bounds__(256) void lif_pass2_kernel(
    const float* __restrict__ h,     // (NT2, COLS)
    const float* __restrict__ lifb,  // (HIDN)
    float* __restrict__ out)
{
    const int chunk = blockIdx.y;                    // 0..63
    const int col   = blockIdx.x * 256 + threadIdx.x;
    const int hid   = col & (HIDN - 1);
    float beta = lifb[hid];
    beta = fminf(fmaxf(beta, 0.0f), 1.0f);

    float* __restrict__ spk  = out;
    float* __restrict__ memo = out + (size_t)NT2 * COLS;

    const int tbase = chunk * CHUNK;
    float mem = (chunk == 0) ? 0.0f : memo[(tbase - 1) * COLS + col];

    constexpr int PF = 16;
    float hv[PF];
#pragma unroll
    for (int i = 0; i < PF; ++i) hv[i] = h[(tbase + i) * COLS + col];

    for (int tt = 0; tt < CHUNK; tt += PF) {
        float hn[PF];
        if (tt + PF < CHUNK) {
#pragma unroll
            for (int i = 0; i < PF; ++i) hn[i] = h[(tbase + tt + PF + i) * COLS + col];
        }
#pragma unroll
        for (int i = 0; i < PF; ++i) {
            const float reset = (mem > 1.0f) ? 1.0f : 0.0f;
            mem = __fsub_rn(__fadd_rn(__fmul_rn(beta, mem), hv[i]), reset);
            const int idx = (tbase + tt + i) * COLS + col;
            spk[idx]  = (mem > 1.0f) ? 1.0f : 0.0f;
            memo[idx] = mem;
        }
#pragma unroll
        for (int i = 0; i < PF; ++i) hv[i] = hn[i];
    }
}

// ---------------------------------------------------------------------------
extern "C" void kernel_launch(void* const* d_in, const int* in_sizes, int n_in,
                              void* d_out, int out_size, void* d_ws, size_t ws_size,
                              hipStream_t stream) {
    const float* x    = (const float*)d_in[0];
    const float* w    = (const float*)d_in[1];
    const float* cb   = (const float*)d_in[2];
    const float* gam  = (const float*)d_in[3];
    const float* bet  = (const float*)d_in[4];
    const float* mean = (const float*)d_in[5];
    const float* var  = (const float*)d_in[6];
    const float* lifb = (const float*)d_in[7];

    float* h = (float*)d_ws;   // 2048*8192 floats = 64 MiB scratch

    dim3 gA(T_LEN / TT, TSUB, NB);   // (8, 4, 64)
    conv_bn_kernel<<<gA, 256, 0, stream>>>(x, w, cb, gam, bet, mean, var, h);

    lif_pass1_kernel<<<COLS / 64, 64, 0, stream>>>(h, lifb, (float*)d_out);

    dim3 gC(COLS / 256, NCHUNK);     // (32, 64) blocks, 8192 waves
    lif_pass2_kernel<<<gC, 256, 0, stream>>>(h, lifb, (float*)d_out);
}

// Round 5
// 268.324 us; speedup vs baseline: 1.0834x; 1.0737x over previous
//
#include <hip/hip_runtime.h>

// Problem constants
#define T_LEN 512
#define CIN   32
#define HIDN  128
#define TSUB  4
#define NB    64
#define TT    64            // t-tile per conv block
#define NT2   2048          // T_LEN*TSUB (scan steps)
#define COLS  8192          // NB*HIDN (parallel scan lanes)
#define CHUNK 32            // pass-2 replay chunk length (steps)
#define NCHUNK (NT2 / CHUNK)

// Transposed h layout: hT[s][col][t]  (s<4, col<8192, t<512)
// t' = 4*t + s ; col = b*HIDN + hid
#define HT_IDX(s, col, t) ((((size_t)(s) * COLS + (size_t)(col)) * T_LEN) + (size_t)(t))

// ---------------------------------------------------------------------------
// Kernel A: Conv1d(k=3,pad=1) + bias + BN(eval) -> hT[s][col][t]
// Compute identical to round 3; only the epilogue store layout changed.
// ---------------------------------------------------------------------------
__global__ __launch_bounds__(256) void conv_bn_kernel(
    const float* __restrict__ x,    // (B, T, CIN)
    const float* __restrict__ w,    // (C_OUT, CIN, 3)
    const float* __restrict__ cb,   // (C_OUT)
    const float* __restrict__ gam,  // (C_OUT)
    const float* __restrict__ bet,  // (C_OUT)
    const float* __restrict__ mean, // (C_OUT)
    const float* __restrict__ var,  // (C_OUT)
    float* __restrict__ hT)         // (TSUB, COLS, T_LEN)
{
    __shared__ float xs[66 * 36];
    __shared__ float ws[128 * 100];  // stride 100: conflict-free float4 reads
    __shared__ float scs[128];
    __shared__ float bbs[128];

    const int t0  = blockIdx.x * TT;
    const int s   = blockIdx.y;
    const int b   = blockIdx.z;
    const int tid = threadIdx.x;

    for (int idx = tid; idx < 66 * 32; idx += 256) {
        int r = idx >> 5, ci = idx & 31;
        int t = t0 + r - 1;
        xs[r * 36 + ci] = (t >= 0 && t < T_LEN) ? x[(b * T_LEN + t) * CIN + ci] : 0.0f;
    }
    for (int idx = tid; idx < 128 * 96; idx += 256) {
        int row = idx / 96, j = idx - row * 96;
        int k = j >> 5, i = j & 31;
        ws[row * 100 + j] = w[(s * HIDN + row) * (CIN * 3) + i * 3 + k];
    }
    if (tid < 128) {
        int c = s * HIDN + tid;
        float sc = gam[c] * rsqrtf(var[c] + 1e-5f);
        scs[tid] = sc;
        bbs[tid] = (cb[c] - mean[c]) * sc + bet[c];
    }
    __syncthreads();

    const int tc = tid & 31;   // hid = tc + cc*32 (4 channels per thread)
    const int tt = tid >> 5;   // 0..7, each handles 8 consecutive t

    float acc[4][8];
#pragma unroll
    for (int a = 0; a < 4; ++a)
#pragma unroll
        for (int q = 0; q < 8; ++q) acc[a][q] = 0.0f;

    for (int j0 = 0; j0 < 96; j0 += 4) {
        const int k  = j0 >> 5;
        const int i0 = j0 & 31;
        float4 wv[4];
#pragma unroll
        for (int cc = 0; cc < 4; ++cc)
            wv[cc] = *reinterpret_cast<const float4*>(&ws[(tc + cc * 32) * 100 + j0]);
#pragma unroll
        for (int tq = 0; tq < 8; ++tq) {
            float4 xv = *reinterpret_cast<const float4*>(&xs[(tt * 8 + tq + k) * 36 + i0]);
#pragma unroll
            for (int cc = 0; cc < 4; ++cc) {
                acc[cc][tq] = fmaf(wv[cc].x, xv.x, acc[cc][tq]);
                acc[cc][tq] = fmaf(wv[cc].y, xv.y, acc[cc][tq]);
                acc[cc][tq] = fmaf(wv[cc].z, xv.z, acc[cc][tq]);
                acc[cc][tq] = fmaf(wv[cc].w, xv.w, acc[cc][tq]);
            }
        }
    }

    // Epilogue: thread's 8 t-values are contiguous in hT -> 2 float4 stores/cc
#pragma unroll
    for (int cc = 0; cc < 4; ++cc) {
        const int hid = tc + cc * 32;
        const float sc = scs[hid], bb = bbs[hid];
        float4 v0, v1;
        v0.x = fmaf(acc[cc][0], sc, bb);
        v0.y = fmaf(acc[cc][1], sc, bb);
        v0.z = fmaf(acc[cc][2], sc, bb);
        v0.w = fmaf(acc[cc][3], sc, bb);
        v1.x = fmaf(acc[cc][4], sc, bb);
        v1.y = fmaf(acc[cc][5], sc, bb);
        v1.z = fmaf(acc[cc][6], sc, bb);
        v1.w = fmaf(acc[cc][7], sc, bb);
        float* dst = hT + HT_IDX(s, b * HIDN + hid, t0 + tt * 8);
        *reinterpret_cast<float4*>(dst)     = v0;
        *reinterpret_cast<float4*>(dst + 4) = v1;
    }
}

// ---------------------------------------------------------------------------
// Kernel B (pass 1): exact serial LIF recurrence over 2048 steps, mem only.
// Per-thread-contiguous float4 loads from hT; rolling 4x4 float4 buffer
// (64 t' lookahead, 16 vmcnt slots). Checkpoints at t' ≡ 31 (mod 32) into
// the mem region of d_out (pass 2 rewrites them bit-identically).
// Op order matches numpy exactly: ((beta*mem) + h) - reset, 3 roundings.
// ---------------------------------------------------------------------------
__global__ __launch_bounds__(64) void lif_pass1_kernel(
    const float* __restrict__ hT,    // (TSUB, COLS, T_LEN)
    const float* __restrict__ lifb,  // (HIDN)
    float* __restrict__ out)
{
    const int col = blockIdx.x * 64 + threadIdx.x;
    const int hid = col & (HIDN - 1);
    float beta = fminf(fmaxf(lifb[hid], 0.0f), 1.0f);

    float* __restrict__ memo = out + (size_t)NT2 * COLS;

    const float4* p[4];
#pragma unroll
    for (int s = 0; s < 4; ++s)
        p[s] = reinterpret_cast<const float4*>(hT + HT_IDX(s, col, 0));

    // hq[slot][s] : slot m&3 holds t = 4m..4m+3 for each s  (16 t' per slot)
    float4 hq[4][4];
#pragma unroll
    for (int bq = 0; bq < 4; ++bq)
#pragma unroll
        for (int s = 0; s < 4; ++s) hq[bq][s] = p[s][bq];

    float mem = 0.0f;

    for (int m0 = 0; m0 < 128; m0 += 4) {   // 128 slots of 16 t' each
#pragma unroll
        for (int bq = 0; bq < 4; ++bq) {
            const int m = m0 + bq;
            const float* hb = reinterpret_cast<const float*>(&hq[bq][0]);
#pragma unroll
            for (int j = 0; j < 16; ++j) {  // t' = 16m + j ; s=j&3, dt=j>>2
                const float hval = hb[(j & 3) * 4 + (j >> 2)];  // static idx
                const float reset = (mem > 1.0f) ? 1.0f : 0.0f;
                mem = __fsub_rn(__fadd_rn(__fmul_rn(beta, mem), hval), reset);
                if (j == 15 && (bq & 1) == 1) {       // t' ≡ 31 (mod 32)
                    const int tp = m * 16 + 15;
                    if (tp < NT2 - 1)
                        memo[(size_t)tp * COLS + col] = mem;
                }
            }
            if (m + 4 < 128) {
#pragma unroll
                for (int s = 0; s < 4; ++s) hq[bq][s] = p[s][m + 4];
            }
        }
    }
}

// ---------------------------------------------------------------------------
// Kernel C (pass 2): 64 chunks x 8192 lanes replay 32 steps each from the
// exact checkpoint and emit all spk/mem outputs. Full-device occupancy,
// write-bandwidth-bound. hT reads are per-thread-contiguous (8 float4).
// ---------------------------------------------------------------------------
__global__ __launch_bounds__(256) void lif_pass2_kernel(
    const float* __restrict__ hT,    // (TSUB, COLS, T_LEN)
    const float* __restrict__ lifb,  // (HIDN)
    float* __restrict__ out)
{
    const int chunk = blockIdx.y;                    // 0..63
    const int col   = blockIdx.x * 256 + threadIdx.x;
    const int hid   = col & (HIDN - 1);
    float beta = fminf(fmaxf(lifb[hid], 0.0f), 1.0f);

    float* __restrict__ spk  = out;
    float* __restrict__ memo = out + (size_t)NT2 * COLS;

    const int tpb = chunk * CHUNK;        // t' base
    const int tb  = tpb >> 2;             // t base (8 t per chunk)

    float4 hq[4][2];                      // [s][0..1] covers t = tb..tb+7
#pragma unroll
    for (int s = 0; s < 4; ++s) {
        const float4* ps = reinterpret_cast<const float4*>(hT + HT_IDX(s, col, tb));
        hq[s][0] = ps[0];
        hq[s][1] = ps[1];
    }

    float mem = (chunk == 0) ? 0.0f : memo[(size_t)(tpb - 1) * COLS + col];

#pragma unroll
    for (int j = 0; j < 32; ++j) {        // t' = tpb + j ; s=j&3, dt=j>>2
        const float* hb = reinterpret_cast<const float*>(&hq[j & 3][0]);
        const float hval = hb[j >> 2];    // static idx (0..7)
        const float reset = (mem > 1.0f) ? 1.0f : 0.0f;
        mem = __fsub_rn(__fadd_rn(__fmul_rn(beta, mem), hval), reset);
        const size_t idx = (size_t)(tpb + j) * COLS + col;
        spk[idx]  = (mem > 1.0f) ? 1.0f : 0.0f;
        memo[idx] = mem;
    }
}

// ---------------------------------------------------------------------------
extern "C" void kernel_launch(void* const* d_in, const int* in_sizes, int n_in,
                              void* d_out, int out_size, void* d_ws, size_t ws_size,
                              hipStream_t stream) {
    const float* x    = (const float*)d_in[0];
    const float* w    = (const float*)d_in[1];
    const float* cb   = (const float*)d_in[2];
    const float* gam  = (const float*)d_in[3];
    const float* bet  = (const float*)d_in[4];
    const float* mean = (const float*)d_in[5];
    const float* var  = (const float*)d_in[6];
    const float* lifb = (const float*)d_in[7];

    float* hT = (float*)d_ws;   // 4*8192*512 floats = 64 MiB scratch

    dim3 gA(T_LEN / TT, TSUB, NB);   // (8, 4, 64)
    conv_bn_kernel<<<gA, 256, 0, stream>>>(x, w, cb, gam, bet, mean, var, hT);

    lif_pass1_kernel<<<COLS / 64, 64, 0, stream>>>(hT, lifb, (float*)d_out);

    dim3 gC(COLS / 256, NCHUNK);     // (32, 64) blocks, 8192 waves
    lif_pass2_kernel<<<gC, 256, 0, stream>>>(hT, lifb, (float*)d_out);
}

// Round 10
// 261.961 us; speedup vs baseline: 1.1097x; 1.0243x over previous
//
#include <hip/hip_runtime.h>

// Problem constants
#define T_LEN 512
#define CIN   32
#define HIDN  128
#define TSUB  4
#define NB    64
#define TT    64            // t-tile per conv block
#define NT2   2048          // T_LEN*TSUB (scan steps)
#define COLS  8192          // NB*HIDN (parallel scan lanes)

// Transposed h layout: hT[s][col][t]  (s<4, col<8192, t<512)
// t' = 4*t + s ; col = b*HIDN + hid
#define HT_IDX(s, col, t) ((((size_t)(s) * COLS + (size_t)(col)) * T_LEN) + (size_t)(t))

// ---------------------------------------------------------------------------
// Kernel A: Conv1d(k=3,pad=1) + bias + BN(eval) -> hT[s][col][t]
// 64 output channels per block: LDS 35.6KB -> 4 blocks/CU (was 2).
// MAC order per output unchanged -> bit-identical results.
// ---------------------------------------------------------------------------
__global__ __launch_bounds__(256) void conv_bn_kernel(
    const float* __restrict__ x,    // (B, T, CIN)
    const float* __restrict__ w,    // (C_OUT, CIN, 3)
    const float* __restrict__ cb,   // (C_OUT)
    const float* __restrict__ gam,  // (C_OUT)
    const float* __restrict__ bet,  // (C_OUT)
    const float* __restrict__ mean, // (C_OUT)
    const float* __restrict__ var,  // (C_OUT)
    float* __restrict__ hT)         // (TSUB, COLS, T_LEN)
{
    __shared__ float xs[66 * 36];    // 9.5 KB
    __shared__ float ws[64 * 100];   // 25.6 KB, stride 100: conflict-light b128
    __shared__ float scs[64];
    __shared__ float bbs[64];

    const int t0  = blockIdx.x * TT;
    const int sg  = blockIdx.y;        // 0..7: s = sg>>1, channel-half = sg&1
    const int s   = sg >> 1;
    const int ch0 = (sg & 1) * 64;
    const int b   = blockIdx.z;
    const int tid = threadIdx.x;

    for (int idx = tid; idx < 66 * 32; idx += 256) {
        int r = idx >> 5, ci = idx & 31;
        int t = t0 + r - 1;
        xs[r * 36 + ci] = (t >= 0 && t < T_LEN) ? x[(b * T_LEN + t) * CIN + ci] : 0.0f;
    }
    for (int idx = tid; idx < 64 * 96; idx += 256) {
        int row = idx / 96, j = idx - row * 96;
        int k = j >> 5, i = j & 31;
        ws[row * 100 + j] = w[(s * HIDN + ch0 + row) * (CIN * 3) + i * 3 + k];
    }
    if (tid < 64) {
        int c = s * HIDN + ch0 + tid;
        float sc = gam[c] * rsqrtf(var[c] + 1e-5f);
        scs[tid] = sc;
        bbs[tid] = (cb[c] - mean[c]) * sc + bet[c];
    }
    __syncthreads();

    const int tc = tid & 31;   // channel-within-half = tc + cc*32 (cc=0..1)
    const int tt = tid >> 5;   // 0..7, each handles 8 consecutive t

    float acc[2][8];
#pragma unroll
    for (int a = 0; a < 2; ++a)
#pragma unroll
        for (int q = 0; q < 8; ++q) acc[a][q] = 0.0f;

    for (int j0 = 0; j0 < 96; j0 += 4) {
        const int k  = j0 >> 5;
        const int i0 = j0 & 31;
        float4 wv[2];
#pragma unroll
        for (int cc = 0; cc < 2; ++cc)
            wv[cc] = *reinterpret_cast<const float4*>(&ws[(tc + cc * 32) * 100 + j0]);
#pragma unroll
        for (int tq = 0; tq < 8; ++tq) {
            float4 xv = *reinterpret_cast<const float4*>(&xs[(tt * 8 + tq + k) * 36 + i0]);
#pragma unroll
            for (int cc = 0; cc < 2; ++cc) {
                acc[cc][tq] = fmaf(wv[cc].x, xv.x, acc[cc][tq]);
                acc[cc][tq] = fmaf(wv[cc].y, xv.y, acc[cc][tq]);
                acc[cc][tq] = fmaf(wv[cc].z, xv.z, acc[cc][tq]);
                acc[cc][tq] = fmaf(wv[cc].w, xv.w, acc[cc][tq]);
            }
        }
    }

    // Epilogue: thread's 8 t-values contiguous in hT -> 2 float4 stores/cc
#pragma unroll
    for (int cc = 0; cc < 2; ++cc) {
        const int cl = tc + cc * 32;
        const float sc = scs[cl], bb = bbs[cl];
        float4 v0, v1;
        v0.x = fmaf(acc[cc][0], sc, bb);
        v0.y = fmaf(acc[cc][1], sc, bb);
        v0.z = fmaf(acc[cc][2], sc, bb);
        v0.w = fmaf(acc[cc][3], sc, bb);
        v1.x = fmaf(acc[cc][4], sc, bb);
        v1.y = fmaf(acc[cc][5], sc, bb);
        v1.z = fmaf(acc[cc][6], sc, bb);
        v1.w = fmaf(acc[cc][7], sc, bb);
        float* dst = hT + HT_IDX(s, b * HIDN + ch0 + cl, t0 + tt * 8);
        *reinterpret_cast<float4*>(dst)     = v0;
        *reinterpret_cast<float4*>(dst + 4) = v1;
    }
}

// ---------------------------------------------------------------------------
// Kernel B (pass 1): exact serial LIF recurrence, mem only.  All h accesses
// are float4 MEMBER reads with literal indices (no address-taking -> SROA to
// registers, rule #20).  Checkpoints every 16 steps (t' ≡ 15 mod 16) into
// the mem region of d_out; pass 2 rewrites them bit-identically.
// Op order matches numpy exactly: ((beta*mem) + h) - reset, 3 roundings.
// NOTE: pasted identifiers are parenthesized -- (hq##B##0).x -- because
// 0.x would otherwise lex as one pp-number token and break the paste.
// ---------------------------------------------------------------------------
#define LIF_STEP(HVAL) { \
    const float reset = (mem > 1.0f) ? 1.0f : 0.0f; \
    mem = __fsub_rn(__fadd_rn(__fmul_rn(beta, mem), (HVAL)), reset); }

// one slot = 16 consecutive t' (t = 4m..4m+3, s = 0..3); then checkpoint+refill
#define SLOT16(B) { \
    LIF_STEP((hq##B##0).x) LIF_STEP((hq##B##1).x) LIF_STEP((hq##B##2).x) LIF_STEP((hq##B##3).x) \
    LIF_STEP((hq##B##0).y) LIF_STEP((hq##B##1).y) LIF_STEP((hq##B##2).y) LIF_STEP((hq##B##3).y) \
    LIF_STEP((hq##B##0).z) LIF_STEP((hq##B##1).z) LIF_STEP((hq##B##2).z) LIF_STEP((hq##B##3).z) \
    LIF_STEP((hq##B##0).w) LIF_STEP((hq##B##1).w) LIF_STEP((hq##B##2).w) LIF_STEP((hq##B##3).w) \
    { const int tp = (m0 + B) * 16 + 15; \
      if (tp < NT2 - 1) memo[(size_t)tp * COLS + col] = mem; } \
    if (m0 + B + 4 < 128) { \
        hq##B##0 = p0[m0 + B + 4]; hq##B##1 = p1[m0 + B + 4]; \
        hq##B##2 = p2[m0 + B + 4]; hq##B##3 = p3[m0 + B + 4]; } }

__global__ __launch_bounds__(64) void lif_pass1_kernel(
    const float* __restrict__ hT,    // (TSUB, COLS, T_LEN)
    const float* __restrict__ lifb,  // (HIDN)
    float* __restrict__ out)
{
    const int col = blockIdx.x * 64 + threadIdx.x;
    const int hid = col & (HIDN - 1);
    float beta = fminf(fmaxf(lifb[hid], 0.0f), 1.0f);

    float* __restrict__ memo = out + (size_t)NT2 * COLS;

    const float4* p0 = reinterpret_cast<const float4*>(hT + HT_IDX(0, col, 0));
    const float4* p1 = reinterpret_cast<const float4*>(hT + HT_IDX(1, col, 0));
    const float4* p2 = reinterpret_cast<const float4*>(hT + HT_IDX(2, col, 0));
    const float4* p3 = reinterpret_cast<const float4*>(hT + HT_IDX(3, col, 0));

    // 4 slots x 4 s, each float4 = 4 t: 64 t' of lookahead
    float4 hq00 = p0[0], hq01 = p1[0], hq02 = p2[0], hq03 = p3[0];
    float4 hq10 = p0[1], hq11 = p1[1], hq12 = p2[1], hq13 = p3[1];
    float4 hq20 = p0[2], hq21 = p1[2], hq22 = p2[2], hq23 = p3[2];
    float4 hq30 = p0[3], hq31 = p1[3], hq32 = p2[3], hq33 = p3[3];

    float mem = 0.0f;

    for (int m0 = 0; m0 < 128; m0 += 4) {
        SLOT16(0)
        SLOT16(1)
        SLOT16(2)
        SLOT16(3)
    }
}

// ---------------------------------------------------------------------------
// Kernel C (pass 2): 128 chunks x 8192 cols; each thread owns 2 adjacent
// cols (float2 stores, 2 independent chains for ILP), replays 16 steps from
// the exact checkpoint.  8192 waves -> full device.
// ---------------------------------------------------------------------------
#define P2_STEP(HV0, HV1, J) { \
    const float r0 = (m0v > 1.0f) ? 1.0f : 0.0f; \
    const float r1 = (m1v > 1.0f) ? 1.0f : 0.0f; \
    m0v = __fsub_rn(__fadd_rn(__fmul_rn(b0, m0v), (HV0)), r0); \
    m1v = __fsub_rn(__fadd_rn(__fmul_rn(b1, m1v), (HV1)), r1); \
    const size_t o = (size_t)(tpb + (J)) * COLS + col0; \
    *reinterpret_cast<float2*>(spk + o)  = \
        make_float2((m0v > 1.0f) ? 1.0f : 0.0f, (m1v > 1.0f) ? 1.0f : 0.0f); \
    *reinterpret_cast<float2*>(memo + o) = make_float2(m0v, m1v); }

__global__ __launch_bounds__(256) void lif_pass2_kernel(
    const float* __restrict__ hT,    // (TSUB, COLS, T_LEN)
    const float* __restrict__ lifb,  // (HIDN)
    float* __restrict__ out)
{
    const int chunk = blockIdx.y;                      // 0..127
    const int c2    = blockIdx.x * 256 + threadIdx.x;  // col-pair id
    const int col0  = c2 * 2;
    const float b0 = fminf(fmaxf(lifb[col0 & (HIDN - 1)], 0.0f), 1.0f);
    const float b1 = fminf(fmaxf(lifb[(col0 + 1) & (HIDN - 1)], 0.0f), 1.0f);

    float* __restrict__ spk  = out;
    float* __restrict__ memo = out + (size_t)NT2 * COLS;

    const int tpb = chunk * 16;           // t' base
    const int tb  = tpb >> 2;             // t base (4 t per chunk)

    // h for 16 t' = one float4 per s per col
    const float4 a0 = *reinterpret_cast<const float4*>(hT + HT_IDX(0, col0, tb));
    const float4 a1 = *reinterpret_cast<const float4*>(hT + HT_IDX(1, col0, tb));
    const float4 a2 = *reinterpret_cast<const float4*>(hT + HT_IDX(2, col0, tb));
    const float4 a3 = *reinterpret_cast<const float4*>(hT + HT_IDX(3, col0, tb));
    const float4 c0 = *reinterpret_cast<const float4*>(hT + HT_IDX(0, col0 + 1, tb));
    const float4 c1 = *reinterpret_cast<const float4*>(hT + HT_IDX(1, col0 + 1, tb));
    const float4 c2v= *reinterpret_cast<const float4*>(hT + HT_IDX(2, col0 + 1, tb));
    const float4 c3 = *reinterpret_cast<const float4*>(hT + HT_IDX(3, col0 + 1, tb));

    float m0v = 0.0f, m1v = 0.0f;
    if (chunk != 0) {
        const float2 ck = *reinterpret_cast<const float2*>(
            memo + (size_t)(tpb - 1) * COLS + col0);
        m0v = ck.x;
        m1v = ck.y;
    }

    P2_STEP(a0.x, c0.x,  0) P2_STEP(a1.x, c1.x,  1) P2_STEP(a2.x, c2v.x,  2) P2_STEP(a3.x, c3.x,  3)
    P2_STEP(a0.y, c0.y,  4) P2_STEP(a1.y, c1.y,  5) P2_STEP(a2.y, c2v.y,  6) P2_STEP(a3.y, c3.y,  7)
    P2_STEP(a0.z, c0.z,  8) P2_STEP(a1.z, c1.z,  9) P2_STEP(a2.z, c2v.z, 10) P2_STEP(a3.z, c3.z, 11)
    P2_STEP(a0.w, c0.w, 12) P2_STEP(a1.w, c1.w, 13) P2_STEP(a2.w, c2v.w, 14) P2_STEP(a3.w, c3.w, 15)
}

// ---------------------------------------------------------------------------
extern "C" void kernel_launch(void* const* d_in, const int* in_sizes, int n_in,
                              void* d_out, int out_size, void* d_ws, size_t ws_size,
                              hipStream_t stream) {
    const float* x    = (const float*)d_in[0];
    const float* w    = (const float*)d_in[1];
    const float* cb   = (const float*)d_in[2];
    const float* gam  = (const float*)d_in[3];
    const float* bet  = (const float*)d_in[4];
    const float* mean = (const float*)d_in[5];
    const float* var  = (const float*)d_in[6];
    const float* lifb = (const float*)d_in[7];

    float* hT = (float*)d_ws;   // 4*8192*512 floats = 64 MiB scratch

    dim3 gA(T_LEN / TT, 8, NB);      // (8 t-tiles, 4s x 2 ch-halves, 64 b)
    conv_bn_kernel<<<gA, 256, 0, stream>>>(x, w, cb, gam, bet, mean, var, hT);

    lif_pass1_kernel<<<COLS / 64, 64, 0, stream>>>(hT, lifb, (float*)d_out);

    dim3 gC(COLS / 2 / 256, NT2 / 16);   // (16, 128) = 2048 blocks
    lif_pass2_kernel<<<gC, 256, 0, stream>>>(hT, lifb, (float*)d_out);
}

// Round 11
// 255.973 us; speedup vs baseline: 1.1357x; 1.0234x over previous
//
#include <hip/hip_runtime.h>

// Problem constants
#define T_LEN 512
#define CIN   32
#define HIDN  128
#define TSUB  4
#define NB    64
#define TT    64            // t-tile per conv block
#define NT2   2048          // T_LEN*TSUB (scan steps)
#define COLS  8192          // NB*HIDN (parallel scan lanes)
#define CHUNK 64            // checkpoint interval / pass-2 replay length
#define NSS   32            // NT2/CHUNK super-slots

// Transposed h layout: hT[s][col][t]  (s<4, col<8192, t<512)
// t' = 4*t + s ; col = b*HIDN + hid
#define HT_IDX(s, col, t) ((((size_t)(s) * COLS + (size_t)(col)) * T_LEN) + (size_t)(t))

// ---------------------------------------------------------------------------
// Kernel A: Conv1d(k=3,pad=1) + bias + BN(eval) -> hT[s][col][t]
// (unchanged from round 10 measurement: 81us, control)
// ---------------------------------------------------------------------------
__global__ __launch_bounds__(256) void conv_bn_kernel(
    const float* __restrict__ x,    // (B, T, CIN)
    const float* __restrict__ w,    // (C_OUT, CIN, 3)
    const float* __restrict__ cb,   // (C_OUT)
    const float* __restrict__ gam,  // (C_OUT)
    const float* __restrict__ bet,  // (C_OUT)
    const float* __restrict__ mean, // (C_OUT)
    const float* __restrict__ var,  // (C_OUT)
    float* __restrict__ hT)         // (TSUB, COLS, T_LEN)
{
    __shared__ float xs[66 * 36];    // 9.5 KB
    __shared__ float ws[64 * 100];   // 25.6 KB
    __shared__ float scs[64];
    __shared__ float bbs[64];

    const int t0  = blockIdx.x * TT;
    const int sg  = blockIdx.y;        // 0..7: s = sg>>1, channel-half = sg&1
    const int s   = sg >> 1;
    const int ch0 = (sg & 1) * 64;
    const int b   = blockIdx.z;
    const int tid = threadIdx.x;

    for (int idx = tid; idx < 66 * 32; idx += 256) {
        int r = idx >> 5, ci = idx & 31;
        int t = t0 + r - 1;
        xs[r * 36 + ci] = (t >= 0 && t < T_LEN) ? x[(b * T_LEN + t) * CIN + ci] : 0.0f;
    }
    for (int idx = tid; idx < 64 * 96; idx += 256) {
        int row = idx / 96, j = idx - row * 96;
        int k = j >> 5, i = j & 31;
        ws[row * 100 + j] = w[(s * HIDN + ch0 + row) * (CIN * 3) + i * 3 + k];
    }
    if (tid < 64) {
        int c = s * HIDN + ch0 + tid;
        float sc = gam[c] * rsqrtf(var[c] + 1e-5f);
        scs[tid] = sc;
        bbs[tid] = (cb[c] - mean[c]) * sc + bet[c];
    }
    __syncthreads();

    const int tc = tid & 31;
    const int tt = tid >> 5;

    float acc[2][8];
#pragma unroll
    for (int a = 0; a < 2; ++a)
#pragma unroll
        for (int q = 0; q < 8; ++q) acc[a][q] = 0.0f;

    for (int j0 = 0; j0 < 96; j0 += 4) {
        const int k  = j0 >> 5;
        const int i0 = j0 & 31;
        float4 wv[2];
#pragma unroll
        for (int cc = 0; cc < 2; ++cc)
            wv[cc] = *reinterpret_cast<const float4*>(&ws[(tc + cc * 32) * 100 + j0]);
#pragma unroll
        for (int tq = 0; tq < 8; ++tq) {
            float4 xv = *reinterpret_cast<const float4*>(&xs[(tt * 8 + tq + k) * 36 + i0]);
#pragma unroll
            for (int cc = 0; cc < 2; ++cc) {
                acc[cc][tq] = fmaf(wv[cc].x, xv.x, acc[cc][tq]);
                acc[cc][tq] = fmaf(wv[cc].y, xv.y, acc[cc][tq]);
                acc[cc][tq] = fmaf(wv[cc].z, xv.z, acc[cc][tq]);
                acc[cc][tq] = fmaf(wv[cc].w, xv.w, acc[cc][tq]);
            }
        }
    }

#pragma unroll
    for (int cc = 0; cc < 2; ++cc) {
        const int cl = tc + cc * 32;
        const float sc = scs[cl], bb = bbs[cl];
        float4 v0, v1;
        v0.x = fmaf(acc[cc][0], sc, bb);
        v0.y = fmaf(acc[cc][1], sc, bb);
        v0.z = fmaf(acc[cc][2], sc, bb);
        v0.w = fmaf(acc[cc][3], sc, bb);
        v1.x = fmaf(acc[cc][4], sc, bb);
        v1.y = fmaf(acc[cc][5], sc, bb);
        v1.z = fmaf(acc[cc][6], sc, bb);
        v1.w = fmaf(acc[cc][7], sc, bb);
        float* dst = hT + HT_IDX(s, b * HIDN + ch0 + cl, t0 + tt * 8);
        *reinterpret_cast<float4*>(dst)     = v0;
        *reinterpret_cast<float4*>(dst + 4) = v1;
    }
}

// ---------------------------------------------------------------------------
// Exact numpy-order LIF step: ((beta*mem) + h) - reset, 3 separate roundings.
// ---------------------------------------------------------------------------
#define LIF_STEP(HVAL) { \
    const float reset = (mem > 1.0f) ? 1.0f : 0.0f; \
    mem = __fsub_rn(__fadd_rn(__fmul_rn(beta, mem), (HVAL)), reset); }

// ---------------------------------------------------------------------------
// Kernel B (pass 1): serial LIF, mem only, checkpoints every 64 steps.
// Triple-buffered register ring: 3 super-slots x 16 float4 (64 t' each) so a
// full 16-load batch (~16KB/wave) is in flight while 128 steps of cover run.
// ---------------------------------------------------------------------------
#define DECL_SS(P) float4 P##00,P##01,P##02,P##03, P##10,P##11,P##12,P##13, \
                          P##20,P##21,P##22,P##23, P##30,P##31,P##32,P##33;

#define LOAD_SS(P, SS) { \
    P##00=p0[(SS)*4+0]; P##01=p0[(SS)*4+1]; P##02=p0[(SS)*4+2]; P##03=p0[(SS)*4+3]; \
    P##10=p1[(SS)*4+0]; P##11=p1[(SS)*4+1]; P##12=p1[(SS)*4+2]; P##13=p1[(SS)*4+3]; \
    P##20=p2[(SS)*4+0]; P##21=p2[(SS)*4+1]; P##22=p2[(SS)*4+2]; P##23=p2[(SS)*4+3]; \
    P##30=p3[(SS)*4+0]; P##31=p3[(SS)*4+1]; P##32=p3[(SS)*4+2]; P##33=p3[(SS)*4+3]; }

// 16 steps: t quad Q (4 t), s=0..3 inner, component = t offset within quad
#define EATQUAD(P, Q) \
    LIF_STEP((P##0##Q).x) LIF_STEP((P##1##Q).x) LIF_STEP((P##2##Q).x) LIF_STEP((P##3##Q).x) \
    LIF_STEP((P##0##Q).y) LIF_STEP((P##1##Q).y) LIF_STEP((P##2##Q).y) LIF_STEP((P##3##Q).y) \
    LIF_STEP((P##0##Q).z) LIF_STEP((P##1##Q).z) LIF_STEP((P##2##Q).z) LIF_STEP((P##3##Q).z) \
    LIF_STEP((P##0##Q).w) LIF_STEP((P##1##Q).w) LIF_STEP((P##2##Q).w) LIF_STEP((P##3##Q).w)

#define EAT_SS(P) EATQUAD(P,0) EATQUAD(P,1) EATQUAD(P,2) EATQUAD(P,3)

#define CKPT(SSV) { const int tp = (SSV) * CHUNK + (CHUNK - 1); \
    if (tp < NT2 - 1) memo[(size_t)tp * COLS + col] = mem; }

__global__ __launch_bounds__(64) void lif_pass1_kernel(
    const float* __restrict__ hT,    // (TSUB, COLS, T_LEN)
    const float* __restrict__ lifb,  // (HIDN)
    float* __restrict__ out)
{
    const int col = blockIdx.x * 64 + threadIdx.x;
    const int hid = col & (HIDN - 1);
    float beta = fminf(fmaxf(lifb[hid], 0.0f), 1.0f);

    float* __restrict__ memo = out + (size_t)NT2 * COLS;

    const float4* p0 = reinterpret_cast<const float4*>(hT + HT_IDX(0, col, 0));
    const float4* p1 = reinterpret_cast<const float4*>(hT + HT_IDX(1, col, 0));
    const float4* p2 = reinterpret_cast<const float4*>(hT + HT_IDX(2, col, 0));
    const float4* p3 = reinterpret_cast<const float4*>(hT + HT_IDX(3, col, 0));

    DECL_SS(rA) DECL_SS(rB) DECL_SS(rC)

    LOAD_SS(rA, 0)
    LOAD_SS(rB, 1)
    LOAD_SS(rC, 2)

    float mem = 0.0f;

    for (int ss = 0; ss < NSS - 2; ss += 3) {   // ss = 0,3,...,27
        EAT_SS(rA) CKPT(ss)
        if (ss + 3 < NSS) LOAD_SS(rA, ss + 3)
        EAT_SS(rB) CKPT(ss + 1)
        if (ss + 4 < NSS) LOAD_SS(rB, ss + 4)
        EAT_SS(rC) CKPT(ss + 2)
        if (ss + 5 < NSS) LOAD_SS(rC, ss + 5)
    }
    // epilogue: super-slots 30 (rA) and 31 (rB); t'=2047 checkpoint skipped
    EAT_SS(rA) CKPT(30)
    EAT_SS(rB)
}

// ---------------------------------------------------------------------------
// Kernel C (pass 2): 32 chunks x 8192 cols, 64-step replay per thread.
// Each thread reads 4 FULL 64B lines (hT[s][col][tb..tb+15]) -> zero read
// overfetch; stores are wave-coalesced 256B. 1024 blocks, 4096 waves.
// ---------------------------------------------------------------------------
#define P2_STEP(HV, J) { \
    const float reset = (mem > 1.0f) ? 1.0f : 0.0f; \
    mem = __fsub_rn(__fadd_rn(__fmul_rn(beta, mem), (HV)), reset); \
    const size_t o = (size_t)(tpb + (J)) * COLS + col; \
    spk[o]  = (mem > 1.0f) ? 1.0f : 0.0f; \
    memo[o] = mem; }

#define P2QUAD(Q) \
    P2_STEP((q0##Q).x, (Q)*16+ 0) P2_STEP((q1##Q).x, (Q)*16+ 1) P2_STEP((q2##Q).x, (Q)*16+ 2) P2_STEP((q3##Q).x, (Q)*16+ 3) \
    P2_STEP((q0##Q).y, (Q)*16+ 4) P2_STEP((q1##Q).y, (Q)*16+ 5) P2_STEP((q2##Q).y, (Q)*16+ 6) P2_STEP((q3##Q).y, (Q)*16+ 7) \
    P2_STEP((q0##Q).z, (Q)*16+ 8) P2_STEP((q1##Q).z, (Q)*16+ 9) P2_STEP((q2##Q).z, (Q)*16+10) P2_STEP((q3##Q).z, (Q)*16+11) \
    P2_STEP((q0##Q).w, (Q)*16+12) P2_STEP((q1##Q).w, (Q)*16+13) P2_STEP((q2##Q).w, (Q)*16+14) P2_STEP((q3##Q).w, (Q)*16+15)

__global__ __launch_bounds__(256) void lif_pass2_kernel(
    const float* __restrict__ hT,    // (TSUB, COLS, T_LEN)
    const float* __restrict__ lifb,  // (HIDN)
    float* __restrict__ out)
{
    const int chunk = blockIdx.y;                      // 0..31
    const int col   = blockIdx.x * 256 + threadIdx.x;
    const int hid   = col & (HIDN - 1);
    float beta = fminf(fmaxf(lifb[hid], 0.0f), 1.0f);

    float* __restrict__ spk  = out;
    float* __restrict__ memo = out + (size_t)NT2 * COLS;

    const int tpb = chunk * CHUNK;        // t' base
    const int tb  = tpb >> 2;             // t base (16 t per chunk)

    // 4 full 64B lines: q[s][quad], quad = 4 consecutive t
    const float4* b0 = reinterpret_cast<const float4*>(hT + HT_IDX(0, col, tb));
    const float4* b1 = reinterpret_cast<const float4*>(hT + HT_IDX(1, col, tb));
    const float4* b2 = reinterpret_cast<const float4*>(hT + HT_IDX(2, col, tb));
    const float4* b3 = reinterpret_cast<const float4*>(hT + HT_IDX(3, col, tb));
    const float4 q00 = b0[0], q01 = b0[1], q02 = b0[2], q03 = b0[3];
    const float4 q10 = b1[0], q11 = b1[1], q12 = b1[2], q13 = b1[3];
    const float4 q20 = b2[0], q21 = b2[1], q22 = b2[2], q23 = b2[3];
    const float4 q30 = b3[0], q31 = b3[1], q32 = b3[2], q33 = b3[3];

    float mem = (chunk == 0) ? 0.0f : memo[(size_t)(tpb - 1) * COLS + col];

    P2QUAD(0) P2QUAD(1) P2QUAD(2) P2QUAD(3)
}

// ---------------------------------------------------------------------------
extern "C" void kernel_launch(void* const* d_in, const int* in_sizes, int n_in,
                              void* d_out, int out_size, void* d_ws, size_t ws_size,
                              hipStream_t stream) {
    const float* x    = (const float*)d_in[0];
    const float* w    = (const float*)d_in[1];
    const float* cb   = (const float*)d_in[2];
    const float* gam  = (const float*)d_in[3];
    const float* bet  = (const float*)d_in[4];
    const float* mean = (const float*)d_in[5];
    const float* var  = (const float*)d_in[6];
    const float* lifb = (const float*)d_in[7];

    float* hT = (float*)d_ws;   // 4*8192*512 floats = 64 MiB scratch

    dim3 gA(T_LEN / TT, 8, NB);      // (8 t-tiles, 4s x 2 ch-halves, 64 b)
    conv_bn_kernel<<<gA, 256, 0, stream>>>(x, w, cb, gam, bet, mean, var, hT);

    lif_pass1_kernel<<<COLS / 64, 64, 0, stream>>>(hT, lifb, (float*)d_out);

    dim3 gC(COLS / 256, NT2 / CHUNK);    // (32, 32) = 1024 blocks
    lif_pass2_kernel<<<gC, 256, 0, stream>>>(hT, lifb, (float*)d_out);
}